// Round 2
// baseline (65.527 us; speedup 1.0000x reference)
//
#include <hip/hip_runtime.h>
#include <hip/hip_bf16.h>
#include <math.h>

typedef __bf16 bf16x8 __attribute__((ext_vector_type(8)));
typedef float  f32x4  __attribute__((ext_vector_type(4)));

#define HW 16384   // 128*128
#define CCH 64
#define OCH 64

// Unnormalized filter taps (normalized on device in fp32, matching reference _norm)
__device__ static const float FIRTAB[62] = {
  // db4 (8)
  -0.0105974017850021f, 0.0328830116668852f, 0.0308413818355607f, -0.1870348117188811f,
  -0.0279837694169839f, 0.6308807679295904f, 0.7148465705529155f, 0.2303778133088964f,
  // db6 (12)
  0.00107730108499558f, -0.00477725751101065f, -0.0005538422009938f, 0.03158203931748603f,
  0.02752286553030533f, -0.0975016055873225f, -0.12976686756709563f, 0.22626469396544f,
  0.3152503517092432f, -0.7511339080210959f, 0.4946238903984534f, 0.1115407433501095f,
  // sym6 (12)
  -0.007800708325034148f, 0.001767711864242804f, 0.04472490177066578f, -0.02106029251230056f,
  -0.0726375227866f, 0.3379294217282401f, 0.787641141030194f, 0.4910559419267466f,
  -0.048311742585632f, -0.1179901111484105f, 0.00349071208421747f, 0.01540410932702737f,
  // coif5 (30)
  -3.459977283621256e-05f, -7.098330313814114e-05f, 0.0004662169601128863f, 0.001117518770890601f,
  -0.002574517688750223f, -0.00900797613666158f, 0.015880544863615904f, 0.03455502757306163f,
  -0.08230192710688598f, -0.07179982161931202f, 0.42848347637761874f, 0.7937772226256206f,
  0.4051769024096169f, -0.06112339000267287f, -0.06577191128185562f, 0.023452696141836267f,
  0.007782596427325418f, -0.003793512864491014f, -0.0002606761356811993f, 0.000107502882505652f,
  1.10319778524429e-05f, -5.520763127949e-06f, -1.0682196848076e-06f, 5.236425333584e-07f,
  1.125098976034e-07f, -5.417490769329e-08f, -8.8631e-09f, 4.2921e-09f, 6.7e-10f, -3.2e-10f
};
__device__ static const int FIR_OFF[4] = {0, 8, 20, 32};
__device__ static const int FIR_LEN[4] = {8, 12, 12, 30};

// ---------------------------------------------------------------------------
// Kernel 1 (unchanged, proven correct): build P_k (64x64) and write bf16 in
// MFMA fragment-linear layout:
//   entry (k, o, c) -> slot[((s*4+mf)*64 + lane)*8 + e]
//   s = 2k + (c>>5), mf = o>>4, lane = (o&15) | (((c&31)>>3)<<4), e = c&7
// ---------------------------------------------------------------------------
__global__ __launch_bounds__(256) void setup_P(
    const float* __restrict__ pw,      // proj_w [64][128]
    const float* __restrict__ s53A, const float* __restrict__ s53D,
    const float* __restrict__ s97A, const float* __restrict__ s97D,
    __bf16* __restrict__ Pout)
{
  __shared__ float matA[64][64];
  __shared__ float matD[64][64];
  __shared__ float tmpA[62][64];
  __shared__ float tmpD[62][64];

  const int k = blockIdx.x;
  const int t = threadIdx.x;

  if (t < 64) {
    const int c = t;
    int Lin;
    if (k < 4) {
      const int L  = FIR_LEN[k];
      const int off = FIR_OFF[k];
      const int pad = (L - 1) / 2;
      const int pl  = pad - 1;
      float ss = 0.f;
      for (int l = 0; l < L; ++l) { float v = FIRTAB[off + l]; ss += v * v; }
      const float inv = 1.f / (sqrtf(ss) + 1e-12f);

      for (int i = 0; i < 62; ++i) { tmpA[i][c] = 0.f; tmpD[i][c] = 0.f; }
      for (int l = 0; l < L; ++l) {
        const float lov = FIRTAB[off + l] * inv;
        const float hiv = ((l & 1) ? -1.f : 1.f) * FIRTAB[off + L - 1 - l] * inv;
        const int base = pl - l;
        int i0 = c + base;
        if (i0 >= 0 && i0 < 62) { tmpA[i0][c] += lov; tmpD[i0][c] += hiv; }
        if (c > 0) {
          int i1 = -c + base;
          if (i1 >= 0 && i1 < 62) { tmpA[i1][c] += lov; tmpD[i1][c] += hiv; }
        }
        if (c < 63) {
          int i2 = 126 - c + base;
          if (i2 >= 0 && i2 < 62) { tmpA[i2][c] += lov; tmpD[i2][c] += hiv; }
        }
      }
      Lin = 62;
    } else {
      for (int i = 0; i < 32; ++i) {
        tmpA[i][c] = (c == 2 * i)     ? 1.f : 0.f;
        tmpD[i][c] = (c == 2 * i + 1) ? 1.f : 0.f;
      }
      float cf[4]; int nst;
      if (k == 4) { cf[0] = -0.5f; cf[1] = 0.25f; cf[2] = 0.f; cf[3] = 0.f; nst = 2; }
      else { cf[0] = -1.586134342f; cf[1] = -0.05298011854f;
             cf[2] = 0.8829110762f; cf[3] = 0.4435068522f; nst = 4; }
      for (int s = 0; s < nst; ++s) {
        if ((s & 1) == 0) {
          for (int i = 0; i < 32; ++i) {
            float a = tmpA[(i == 0) ? 1 : i - 1][c];
            float b2 = tmpA[(i == 31) ? 30 : i + 1][c];
            tmpD[i][c] += cf[s] * 0.5f * (a + b2);
          }
        } else {
          for (int i = 0; i < 32; ++i) {
            float a = tmpD[(i == 0) ? 1 : i - 1][c];
            float b2 = tmpD[(i == 31) ? 30 : i + 1][c];
            tmpA[i][c] += cf[s] * 0.5f * (a + b2);
          }
        }
      }
      Lin = 32;
    }
    float sA = 1.f, sD = 1.f;
    if (k == 4) { sA = s53A[0]; sD = s53D[0]; }
    if (k == 5) { sA = s97A[0]; sD = s97D[0]; }
    const float step = (float)Lin / 64.0f;
    for (int o = 0; o < 64; ++o) {
      float src = (o + 0.5f) * step - 0.5f;
      src = fmaxf(src, 0.f);
      int i0 = (int)floorf(src); if (i0 > Lin - 1) i0 = Lin - 1;
      int i1 = i0 + 1;           if (i1 > Lin - 1) i1 = Lin - 1;
      float w = src - (float)i0;
      matA[o][c] = sA * ((1.f - w) * tmpA[i0][c] + w * tmpA[i1][c]);
      matD[o][c] = sD * ((1.f - w) * tmpD[i0][c] + w * tmpD[i1][c]);
    }
  }
  __syncthreads();

  const int o  = t & 63;
  const int cb = (t >> 6) * 16;
  float acc[16];
  #pragma unroll
  for (int cc = 0; cc < 16; ++cc) acc[cc] = 0.f;
  for (int j = 0; j < 64; ++j) {
    const float wa = pw[o * 128 + j];
    const float wd = pw[o * 128 + 64 + j];
    #pragma unroll
    for (int cc = 0; cc < 16; ++cc)
      acc[cc] += wa * matA[j][cb + cc] + wd * matD[j][cb + cc];
  }
  const int mf = o >> 4;
  #pragma unroll
  for (int cc = 0; cc < 16; ++cc) {
    const int c = cb + cc;
    const int s = k * 2 + (c >> 5);
    const int lane = (o & 15) | (((c & 31) >> 3) << 4);
    const int e = c & 7;
    Pout[(((s * 4 + mf) * 64 + lane) << 3) + e] = (__bf16)acc[cc];
  }
}

// ---------------------------------------------------------------------------
// Kernel 2 (restructured for occupancy + memory overlap):
//  - 1024 blocks x 256 threads; 128 pixels/block; LDS = 28 KB -> 4-5 blocks/CU
//  - P fragments live in 12 VGPRs/wave (loaded from L2-hot global, no LDS)
//  - all 256 threads load x (2 threads/pixel, 32 channels each); gate MLP
//    split into two fp32 partial dot-products combined via LDS
//  - xtr: [128][64] bf16, XOR-swizzled in 16B units -> conflict-minimal
//    ds_write_b128 / ds_read_b128
// ---------------------------------------------------------------------------
__global__ __launch_bounds__(256, 4) void wavelet_main(
    const float* __restrict__ xg,
    const float* __restrict__ gw1, const float* __restrict__ gb1,
    const float* __restrict__ gw2, const float* __restrict__ gb2,
    const float* __restrict__ pbias,
    const __bf16* __restrict__ Pws,
    float* __restrict__ outg)
{
  __shared__ __align__(16) unsigned char xtr[128 * 128];  // 16 KB: [pixel][64 bf16] swizzled
  __shared__ __align__(16) float hpart[128 * 16];         //  8 KB: partial h (upper half), swizzled f32x4
  __shared__ __align__(16) float wmld[128 * 8];           //  4 KB: gate weights per pixel

  const int t     = threadIdx.x;
  const int blk   = blockIdx.x;
  const int b     = blk >> 7;
  const int pbase = (blk & 127) << 7;
  const int p     = t & 127;
  const int half  = t >> 7;     // channel half this thread loads

  // ---- phase 1: cooperative x load (all 256 threads, 32 channels each) ----
  const float* xp = xg + (size_t)b * (CCH * HW) + (size_t)(half * 32) * HW + (pbase + p);
  float xr[32];
  #pragma unroll
  for (int i = 0; i < 32; ++i) xr[i] = xp[(size_t)i * HW];

  // bf16 pack into swizzled xtr: channel unit u = c>>3, slot u^(p&7)
  #pragma unroll
  for (int i = 0; i < 4; ++i) {
    bf16x8 v;
    #pragma unroll
    for (int e = 0; e < 8; ++e) v[e] = (__bf16)xr[i * 8 + e];
    const int u = half * 4 + i;
    *(bf16x8*)&xtr[p * 128 + ((u ^ (p & 7)) << 4)] = v;
  }

  // gate MLP partial: hp[g] = sum over my 32 channels
  float hp[16];
  #pragma unroll
  for (int g = 0; g < 16; ++g) {
    float a = 0.f;
    const float* wrow = gw1 + g * 64 + half * 32;
    #pragma unroll
    for (int i = 0; i < 32; ++i) a += xr[i] * wrow[i];
    hp[g] = a;
  }
  if (half) {
    #pragma unroll
    for (int q = 0; q < 4; ++q) {
      f32x4 v = { hp[q*4+0], hp[q*4+1], hp[q*4+2], hp[q*4+3] };
      *(f32x4*)&hpart[p * 16 + ((q ^ (p & 3)) << 2)] = v;
    }
  }
  __syncthreads();

  // ---- A-fragment loads (per wave, 12x 16B from L2-hot Pws) ----
  const int w    = t >> 6;
  const int lane = t & 63;
  bf16x8 A[12];
  #pragma unroll
  for (int kk = 0; kk < 6; ++kk)
    #pragma unroll
    for (int sh = 0; sh < 2; ++sh)
      A[kk * 2 + sh] = *(const bf16x8*)(Pws + (size_t)((((2 * kk + sh) * 4 + w) * 64 + lane) << 3));

  // ---- finish gate MLP + softmax (threads with half==0 only) ----
  if (!half) {
    float h[16];
    #pragma unroll
    for (int q = 0; q < 4; ++q) {
      f32x4 v = *(f32x4*)&hpart[p * 16 + ((q ^ (p & 3)) << 2)];
      #pragma unroll
      for (int j = 0; j < 4; ++j) h[q*4+j] = fmaxf(hp[q*4+j] + v[j] + gb1[q*4+j], 0.f);
    }
    float lg[6];
    #pragma unroll
    for (int kk = 0; kk < 6; ++kk) {
      float a = gb2[kk];
      #pragma unroll
      for (int g = 0; g < 16; ++g) a += h[g] * gw2[kk * 16 + g];
      lg[kk] = a;
    }
    float mx = lg[0];
    #pragma unroll
    for (int kk = 1; kk < 6; ++kk) mx = fmaxf(mx, lg[kk]);
    float ex[6], ssum = 0.f;
    #pragma unroll
    for (int kk = 0; kk < 6; ++kk) { ex[kk] = expf(lg[kk] - mx); ssum += ex[kk]; }
    float g6[6], wsum = 0.f;
    #pragma unroll
    for (int kk = 0; kk < 6; ++kk) { g6[kk] = ex[kk] / ssum; wsum += g6[kk]; }
    const float winv = 1.f / (wsum + 1e-12f);
    f32x4 w0 = { g6[0]*winv, g6[1]*winv, g6[2]*winv, g6[3]*winv };
    f32x4 w1 = { g6[4]*winv, g6[5]*winv, 0.f, 0.f };
    *(f32x4*)&wmld[p * 8 + 0] = w0;
    *(f32x4*)&wmld[p * 8 + 4] = w1;
  }
  __syncthreads();

  // ---- MFMA phase: wave w owns output rows mf=w; 8 pixel-groups of 16 ----
  const int lr = lane & 15;
  const int kq = lane >> 4;

  float bias[4];
  #pragma unroll
  for (int j = 0; j < 4; ++j) bias[j] = pbias[w * 16 + kq * 4 + j];

  float* outbase = outg + (size_t)b * (OCH * HW) + pbase;

  #pragma unroll 2
  for (int pg = 0; pg < 8; ++pg) {
    const int col = pg * 16 + lr;
    const bf16x8 B0 = *(const bf16x8*)&xtr[col * 128 + ((kq       ^ (col & 7)) << 4)];
    const bf16x8 B1 = *(const bf16x8*)&xtr[col * 128 + (((4 + kq) ^ (col & 7)) << 4)];
    const f32x4 wv0 = *(const f32x4*)&wmld[col * 8 + 0];
    const f32x4 wv1 = *(const f32x4*)&wmld[col * 8 + 4];
    const float wmv[6] = { wv0[0], wv0[1], wv0[2], wv0[3], wv1[0], wv1[1] };

    f32x4 facc = {0.f, 0.f, 0.f, 0.f};
    #pragma unroll
    for (int kk = 0; kk < 6; ++kk) {
      f32x4 y = {0.f, 0.f, 0.f, 0.f};
      y = __builtin_amdgcn_mfma_f32_16x16x32_bf16(A[2 * kk    ], B0, y, 0, 0, 0);
      y = __builtin_amdgcn_mfma_f32_16x16x32_bf16(A[2 * kk + 1], B1, y, 0, 0, 0);
      #pragma unroll
      for (int j = 0; j < 4; ++j) facc[j] += wmv[kk] * y[j];
    }
    #pragma unroll
    for (int j = 0; j < 4; ++j) {
      const int o = w * 16 + kq * 4 + j;
      outbase[(size_t)o * HW + col] = facc[j] + bias[j];
    }
  }
}

extern "C" void kernel_launch(void* const* d_in, const int* in_sizes, int n_in,
                              void* d_out, int out_size, void* d_ws, size_t ws_size,
                              hipStream_t stream) {
  const float* x    = (const float*)d_in[0];
  const float* gw1  = (const float*)d_in[1];
  const float* gb1  = (const float*)d_in[2];
  const float* gw2  = (const float*)d_in[3];
  const float* gb2  = (const float*)d_in[4];
  const float* pw   = (const float*)d_in[5];
  const float* pb   = (const float*)d_in[6];
  const float* s53A = (const float*)d_in[7];
  const float* s53D = (const float*)d_in[8];
  const float* s97A = (const float*)d_in[9];
  const float* s97D = (const float*)d_in[10];
  __bf16* Pws = (__bf16*)d_ws;
  float* out = (float*)d_out;

  setup_P<<<6, 256, 0, stream>>>(pw, s53A, s53D, s97A, s97D, Pws);
  wavelet_main<<<1024, 256, 0, stream>>>(x, gw1, gb1, gw2, gb2, pb, Pws, out);
}

// Round 3
// 45.159 us; speedup vs baseline: 1.4510x; 1.4510x over previous
//
#include <hip/hip_runtime.h>
#include <hip/hip_bf16.h>
#include <math.h>

typedef __bf16 bf16x8 __attribute__((ext_vector_type(8)));
typedef float  f32x4  __attribute__((ext_vector_type(4)));

#define HW 16384   // 128*128
#define CCH 64
#define OCH 64

__device__ static const float FIRTAB[62] = {
  // db4 (8)
  -0.0105974017850021f, 0.0328830116668852f, 0.0308413818355607f, -0.1870348117188811f,
  -0.0279837694169839f, 0.6308807679295904f, 0.7148465705529155f, 0.2303778133088964f,
  // db6 (12)
  0.00107730108499558f, -0.00477725751101065f, -0.0005538422009938f, 0.03158203931748603f,
  0.02752286553030533f, -0.0975016055873225f, -0.12976686756709563f, 0.22626469396544f,
  0.3152503517092432f, -0.7511339080210959f, 0.4946238903984534f, 0.1115407433501095f,
  // sym6 (12)
  -0.007800708325034148f, 0.001767711864242804f, 0.04472490177066578f, -0.02106029251230056f,
  -0.0726375227866f, 0.3379294217282401f, 0.787641141030194f, 0.4910559419267466f,
  -0.048311742585632f, -0.1179901111484105f, 0.00349071208421747f, 0.01540410932702737f,
  // coif5 (30)
  -3.459977283621256e-05f, -7.098330313814114e-05f, 0.0004662169601128863f, 0.001117518770890601f,
  -0.002574517688750223f, -0.00900797613666158f, 0.015880544863615904f, 0.03455502757306163f,
  -0.08230192710688598f, -0.07179982161931202f, 0.42848347637761874f, 0.7937772226256206f,
  0.4051769024096169f, -0.06112339000267287f, -0.06577191128185562f, 0.023452696141836267f,
  0.007782596427325418f, -0.003793512864491014f, -0.0002606761356811993f, 0.000107502882505652f,
  1.10319778524429e-05f, -5.520763127949e-06f, -1.0682196848076e-06f, 5.236425333584e-07f,
  1.125098976034e-07f, -5.417490769329e-08f, -8.8631e-09f, 4.2921e-09f, 6.7e-10f, -3.2e-10f
};
__device__ static const int FIR_OFF[4] = {0, 8, 20, 32};
__device__ static const int FIR_LEN[4] = {8, 12, 12, 30};

// ---------------------------------------------------------------------------
// Kernel 1: build P_k (64x64), fragment-linear bf16 output (layout proven in
// rounds 1-2). 24 blocks: k = bid>>2 builds redundantly, q = bid&3 folds its
// 16 output rows -> ~4x faster fold, ~1-2 us total.
//   entry (k, o, c) -> Pout[(((s*4+mf)*64 + lane)*8 + e]
//   s = 2k + (c>>5), mf = o>>4, lane = (o&15) | (((c&31)>>3)<<4), e = c&7
// ---------------------------------------------------------------------------
__global__ __launch_bounds__(256) void setup_P(
    const float* __restrict__ pw,      // proj_w [64][128]
    const float* __restrict__ s53A, const float* __restrict__ s53D,
    const float* __restrict__ s97A, const float* __restrict__ s97D,
    __bf16* __restrict__ Pout)
{
  __shared__ float matA[64][64];
  __shared__ float matD[64][64];
  __shared__ float tmpA[62][64];
  __shared__ float tmpD[62][64];

  const int k = blockIdx.x >> 2;
  const int q = blockIdx.x & 3;
  const int t = threadIdx.x;

  if (t < 64) {
    const int c = t;
    int Lin;
    if (k < 4) {
      const int L  = FIR_LEN[k];
      const int off = FIR_OFF[k];
      const int pad = (L - 1) / 2;
      const int pl  = pad - 1;
      float ss = 0.f;
      for (int l = 0; l < L; ++l) { float v = FIRTAB[off + l]; ss += v * v; }
      const float inv = 1.f / (sqrtf(ss) + 1e-12f);

      for (int i = 0; i < 62; ++i) { tmpA[i][c] = 0.f; tmpD[i][c] = 0.f; }
      for (int l = 0; l < L; ++l) {
        const float lov = FIRTAB[off + l] * inv;
        const float hiv = ((l & 1) ? -1.f : 1.f) * FIRTAB[off + L - 1 - l] * inv;
        const int base = pl - l;
        int i0 = c + base;
        if (i0 >= 0 && i0 < 62) { tmpA[i0][c] += lov; tmpD[i0][c] += hiv; }
        if (c > 0) {
          int i1 = -c + base;
          if (i1 >= 0 && i1 < 62) { tmpA[i1][c] += lov; tmpD[i1][c] += hiv; }
        }
        if (c < 63) {
          int i2 = 126 - c + base;
          if (i2 >= 0 && i2 < 62) { tmpA[i2][c] += lov; tmpD[i2][c] += hiv; }
        }
      }
      Lin = 62;
    } else {
      for (int i = 0; i < 32; ++i) {
        tmpA[i][c] = (c == 2 * i)     ? 1.f : 0.f;
        tmpD[i][c] = (c == 2 * i + 1) ? 1.f : 0.f;
      }
      float cf[4]; int nst;
      if (k == 4) { cf[0] = -0.5f; cf[1] = 0.25f; cf[2] = 0.f; cf[3] = 0.f; nst = 2; }
      else { cf[0] = -1.586134342f; cf[1] = -0.05298011854f;
             cf[2] = 0.8829110762f; cf[3] = 0.4435068522f; nst = 4; }
      for (int s = 0; s < nst; ++s) {
        if ((s & 1) == 0) {
          for (int i = 0; i < 32; ++i) {
            float a = tmpA[(i == 0) ? 1 : i - 1][c];
            float b2 = tmpA[(i == 31) ? 30 : i + 1][c];
            tmpD[i][c] += cf[s] * 0.5f * (a + b2);
          }
        } else {
          for (int i = 0; i < 32; ++i) {
            float a = tmpD[(i == 0) ? 1 : i - 1][c];
            float b2 = tmpD[(i == 31) ? 30 : i + 1][c];
            tmpA[i][c] += cf[s] * 0.5f * (a + b2);
          }
        }
      }
      Lin = 32;
    }
    float sA = 1.f, sD = 1.f;
    if (k == 4) { sA = s53A[0]; sD = s53D[0]; }
    if (k == 5) { sA = s97A[0]; sD = s97D[0]; }
    const float step = (float)Lin / 64.0f;
    for (int o = 0; o < 64; ++o) {
      float src = (o + 0.5f) * step - 0.5f;
      src = fmaxf(src, 0.f);
      int i0 = (int)floorf(src); if (i0 > Lin - 1) i0 = Lin - 1;
      int i1 = i0 + 1;           if (i1 > Lin - 1) i1 = Lin - 1;
      float w = src - (float)i0;
      matA[o][c] = sA * ((1.f - w) * tmpA[i0][c] + w * tmpA[i1][c]);
      matD[o][c] = sD * ((1.f - w) * tmpD[i0][c] + w * tmpD[i1][c]);
    }
  }
  __syncthreads();

  // fold: this block handles output rows o = q*16 .. q*16+15
  const int o  = q * 16 + (t & 15);
  const int c0 = (t >> 4) * 4;
  float acc[4] = {0.f, 0.f, 0.f, 0.f};
  for (int j = 0; j < 64; ++j) {
    const float wa = pw[o * 128 + j];
    const float wd = pw[o * 128 + 64 + j];
    #pragma unroll
    for (int cc = 0; cc < 4; ++cc)
      acc[cc] += wa * matA[j][c0 + cc] + wd * matD[j][c0 + cc];
  }
  #pragma unroll
  for (int cc = 0; cc < 4; ++cc) {
    const int c = c0 + cc;
    const int s = k * 2 + (c >> 5);
    const int lane = (o & 15) | (((c & 31) >> 3) << 4);
    const int e = c & 7;
    Pout[(((s * 4 + q) * 64 + lane) << 3) + e] = (__bf16)acc[cc];
  }
}

// ---------------------------------------------------------------------------
// Kernel 2: latency-fixed main kernel.
//  Phase 0: x tile loaded as float4 ALONG PIXELS (8 independent 1KB wave
//           loads/thread) into fp32 LDS [c][128] with 64B rotation per
//           (c>>3)&1 to split bank sets.
//  Phase 1: thread-per-pixel gate MLP (fp32) from LDS column gather.
//  Phase 2: per-wave MFMA; B-frags gathered from fp32 LDS (2-way min
//           conflicts) + bf16 convert in-register; A-frags in 48 VGPRs,
//           loaded from Pws before barrier 1 so latency hides under gate.
//  LDS 36 KB -> 4 blocks/CU; launch_bounds(256,4) -> 128 VGPR cap.
// ---------------------------------------------------------------------------
__global__ __launch_bounds__(256, 4) void wavelet_main(
    const float* __restrict__ xg,
    const float* __restrict__ gw1, const float* __restrict__ gb1,
    const float* __restrict__ gw2, const float* __restrict__ gb2,
    const float* __restrict__ pbias,
    const __bf16* __restrict__ Pws,
    float* __restrict__ outg)
{
  __shared__ __align__(16) float xf32[64 * 128];   // 32 KB, rotated rows
  __shared__ __align__(16) float wmld[128 * 8];    //  4 KB

  const int t     = threadIdx.x;
  const int blk   = blockIdx.x;
  const int b     = blk >> 7;
  const int pbase = (blk & 127) << 7;
  const int w     = t >> 6;
  const int lane  = t & 63;

  // ---- phase 0: coalesced float4 x loads (8 independent per thread) ----
  {
    const int fu   = lane & 31;            // float4 unit along pixels
    const int chh  = (lane >> 5) * 8;      // channel sub-base
    const float* src = xg + (size_t)b * (CCH * HW) + pbase + fu * 4;
    float4 v[8];
    #pragma unroll
    for (int i = 0; i < 8; ++i) {
      const int c = w * 16 + chh + i;
      v[i] = *(const float4*)(src + (size_t)c * HW);
    }
    float4* dst = (float4*)xf32;
    #pragma unroll
    for (int i = 0; i < 8; ++i) {
      const int c = w * 16 + chh + i;
      dst[c * 32 + ((fu + ((c >> 3) & 1) * 4) & 31)] = v[i];
    }
  }

  // ---- A-fragment loads (12 x 1KB/wave, latency hidden under phase 1) ----
  bf16x8 A[12];
  #pragma unroll
  for (int kk = 0; kk < 6; ++kk)
    #pragma unroll
    for (int sh = 0; sh < 2; ++sh)
      A[kk * 2 + sh] = *(const bf16x8*)(Pws + (size_t)((((2 * kk + sh) * 4 + w) * 64 + lane) << 3));

  __syncthreads();

  // ---- phase 1: gate MLP + softmax, thread-per-pixel (t < 128) ----
  if (t < 128) {
    const int p = t;
    float acc[16];
    #pragma unroll
    for (int g = 0; g < 16; ++g) acc[g] = gb1[g];
    #pragma unroll
    for (int c8 = 0; c8 < 8; ++c8) {
      const int pp = (p + (c8 & 1) * 16) & 127;   // rotation for rows c8*8..+7
      float xv[8];
      #pragma unroll
      for (int e = 0; e < 8; ++e) xv[e] = xf32[(c8 * 8 + e) * 128 + pp];
      #pragma unroll
      for (int g = 0; g < 16; ++g) {
        #pragma unroll
        for (int e = 0; e < 8; ++e)
          acc[g] += xv[e] * gw1[g * 64 + c8 * 8 + e];
      }
    }
    float h[16];
    #pragma unroll
    for (int g = 0; g < 16; ++g) h[g] = fmaxf(acc[g], 0.f);
    float lg[6];
    #pragma unroll
    for (int kk = 0; kk < 6; ++kk) {
      float a = gb2[kk];
      #pragma unroll
      for (int g = 0; g < 16; ++g) a += h[g] * gw2[kk * 16 + g];
      lg[kk] = a;
    }
    float mx = lg[0];
    #pragma unroll
    for (int kk = 1; kk < 6; ++kk) mx = fmaxf(mx, lg[kk]);
    float ex[6], ssum = 0.f;
    #pragma unroll
    for (int kk = 0; kk < 6; ++kk) { ex[kk] = expf(lg[kk] - mx); ssum += ex[kk]; }
    float g6[6], wsum = 0.f;
    #pragma unroll
    for (int kk = 0; kk < 6; ++kk) { g6[kk] = ex[kk] / ssum; wsum += g6[kk]; }
    const float winv = 1.f / (wsum + 1e-12f);
    f32x4 w0 = { g6[0]*winv, g6[1]*winv, g6[2]*winv, g6[3]*winv };
    f32x4 w1 = { g6[4]*winv, g6[5]*winv, 0.f, 0.f };
    *(f32x4*)&wmld[p * 8 + 0] = w0;
    *(f32x4*)&wmld[p * 8 + 4] = w1;
  }
  __syncthreads();

  // ---- phase 2: MFMA. wave w owns output rows w*16..+15, 8 groups of 16 px
  const int lr = lane & 15;
  const int kq = lane >> 4;
  const int rot = (kq & 1) * 16;   // rotation (floats) for all B channels

  float bias[4];
  #pragma unroll
  for (int j = 0; j < 4; ++j) bias[j] = pbias[w * 16 + kq * 4 + j];

  float* outbase = outg + (size_t)b * (OCH * HW) + pbase;

  #pragma unroll 2
  for (int pg = 0; pg < 8; ++pg) {
    const int col = pg * 16 + lr;
    const int cb  = (col + rot) & 127;

    float b0f[8], b1f[8];
    #pragma unroll
    for (int e = 0; e < 8; ++e) {
      b0f[e] = xf32[(kq * 8 + e) * 128 + cb];
      b1f[e] = xf32[(32 + kq * 8 + e) * 128 + cb];
    }
    bf16x8 B0, B1;
    #pragma unroll
    for (int e = 0; e < 8; ++e) { B0[e] = (__bf16)b0f[e]; B1[e] = (__bf16)b1f[e]; }

    const f32x4 wv0 = *(const f32x4*)&wmld[col * 8 + 0];
    const f32x4 wv1 = *(const f32x4*)&wmld[col * 8 + 4];
    const float wmv[6] = { wv0[0], wv0[1], wv0[2], wv0[3], wv1[0], wv1[1] };

    f32x4 facc = {0.f, 0.f, 0.f, 0.f};
    #pragma unroll
    for (int kk = 0; kk < 6; ++kk) {
      f32x4 y = {0.f, 0.f, 0.f, 0.f};
      y = __builtin_amdgcn_mfma_f32_16x16x32_bf16(A[2 * kk    ], B0, y, 0, 0, 0);
      y = __builtin_amdgcn_mfma_f32_16x16x32_bf16(A[2 * kk + 1], B1, y, 0, 0, 0);
      #pragma unroll
      for (int j = 0; j < 4; ++j) facc[j] += wmv[kk] * y[j];
    }
    #pragma unroll
    for (int j = 0; j < 4; ++j) {
      const int o = w * 16 + kq * 4 + j;
      outbase[(size_t)o * HW + col] = facc[j] + bias[j];
    }
  }
}

extern "C" void kernel_launch(void* const* d_in, const int* in_sizes, int n_in,
                              void* d_out, int out_size, void* d_ws, size_t ws_size,
                              hipStream_t stream) {
  const float* x    = (const float*)d_in[0];
  const float* gw1  = (const float*)d_in[1];
  const float* gb1  = (const float*)d_in[2];
  const float* gw2  = (const float*)d_in[3];
  const float* gb2  = (const float*)d_in[4];
  const float* pw   = (const float*)d_in[5];
  const float* pb   = (const float*)d_in[6];
  const float* s53A = (const float*)d_in[7];
  const float* s53D = (const float*)d_in[8];
  const float* s97A = (const float*)d_in[9];
  const float* s97D = (const float*)d_in[10];
  __bf16* Pws = (__bf16*)d_ws;
  float* out = (float*)d_out;

  setup_P<<<24, 256, 0, stream>>>(pw, s53A, s53D, s97A, s97D, Pws);
  wavelet_main<<<1024, 256, 0, stream>>>(x, gw1, gb1, gw2, gb2, pb, Pws, out);
}

// Round 4
// 42.143 us; speedup vs baseline: 1.5549x; 1.0716x over previous
//
#include <hip/hip_runtime.h>
#include <hip/hip_bf16.h>
#include <math.h>

typedef __bf16 bf16x4 __attribute__((ext_vector_type(4)));
typedef __bf16 bf16x8 __attribute__((ext_vector_type(8)));
typedef float  f32x4  __attribute__((ext_vector_type(4)));

#define HW 16384   // 128*128
#define CCH 64
#define OCH 64
#define XSTR 144   // bytes per LDS pixel row (128 data + 16 pad, 16B aligned)

__device__ static const float FIRTAB[62] = {
  // db4 (8)
  -0.0105974017850021f, 0.0328830116668852f, 0.0308413818355607f, -0.1870348117188811f,
  -0.0279837694169839f, 0.6308807679295904f, 0.7148465705529155f, 0.2303778133088964f,
  // db6 (12)
  0.00107730108499558f, -0.00477725751101065f, -0.0005538422009938f, 0.03158203931748603f,
  0.02752286553030533f, -0.0975016055873225f, -0.12976686756709563f, 0.22626469396544f,
  0.3152503517092432f, -0.7511339080210959f, 0.4946238903984534f, 0.1115407433501095f,
  // sym6 (12)
  -0.007800708325034148f, 0.001767711864242804f, 0.04472490177066578f, -0.02106029251230056f,
  -0.0726375227866f, 0.3379294217282401f, 0.787641141030194f, 0.4910559419267466f,
  -0.048311742585632f, -0.1179901111484105f, 0.00349071208421747f, 0.01540410932702737f,
  // coif5 (30)
  -3.459977283621256e-05f, -7.098330313814114e-05f, 0.0004662169601128863f, 0.001117518770890601f,
  -0.002574517688750223f, -0.00900797613666158f, 0.015880544863615904f, 0.03455502757306163f,
  -0.08230192710688598f, -0.07179982161931202f, 0.42848347637761874f, 0.7937772226256206f,
  0.4051769024096169f, -0.06112339000267287f, -0.06577191128185562f, 0.023452696141836267f,
  0.007782596427325418f, -0.003793512864491014f, -0.0002606761356811993f, 0.000107502882505652f,
  1.10319778524429e-05f, -5.520763127949e-06f, -1.0682196848076e-06f, 5.236425333584e-07f,
  1.125098976034e-07f, -5.417490769329e-08f, -8.8631e-09f, 4.2921e-09f, 6.7e-10f, -3.2e-10f
};
__device__ static const int FIR_OFF[4] = {0, 8, 20, 32};
__device__ static const int FIR_LEN[4] = {8, 12, 12, 30};

// ---------------------------------------------------------------------------
// Kernel 1 (proven): build P_k (64x64), fragment-linear bf16 output.
//   entry (k, o, c) -> Pout[(((s*4+mf)*64 + lane)*8 + e]
//   s = 2k + (c>>5), mf = o>>4, lane = (o&15) | (((c&31)>>3)<<4), e = c&7
// ---------------------------------------------------------------------------
__global__ __launch_bounds__(256) void setup_P(
    const float* __restrict__ pw,
    const float* __restrict__ s53A, const float* __restrict__ s53D,
    const float* __restrict__ s97A, const float* __restrict__ s97D,
    __bf16* __restrict__ Pout)
{
  __shared__ float matA[64][64];
  __shared__ float matD[64][64];
  __shared__ float tmpA[62][64];
  __shared__ float tmpD[62][64];

  const int k = blockIdx.x >> 2;
  const int q = blockIdx.x & 3;
  const int t = threadIdx.x;

  if (t < 64) {
    const int c = t;
    int Lin;
    if (k < 4) {
      const int L  = FIR_LEN[k];
      const int off = FIR_OFF[k];
      const int pad = (L - 1) / 2;
      const int pl  = pad - 1;
      float ss = 0.f;
      for (int l = 0; l < L; ++l) { float v = FIRTAB[off + l]; ss += v * v; }
      const float inv = 1.f / (sqrtf(ss) + 1e-12f);

      for (int i = 0; i < 62; ++i) { tmpA[i][c] = 0.f; tmpD[i][c] = 0.f; }
      for (int l = 0; l < L; ++l) {
        const float lov = FIRTAB[off + l] * inv;
        const float hiv = ((l & 1) ? -1.f : 1.f) * FIRTAB[off + L - 1 - l] * inv;
        const int base = pl - l;
        int i0 = c + base;
        if (i0 >= 0 && i0 < 62) { tmpA[i0][c] += lov; tmpD[i0][c] += hiv; }
        if (c > 0) {
          int i1 = -c + base;
          if (i1 >= 0 && i1 < 62) { tmpA[i1][c] += lov; tmpD[i1][c] += hiv; }
        }
        if (c < 63) {
          int i2 = 126 - c + base;
          if (i2 >= 0 && i2 < 62) { tmpA[i2][c] += lov; tmpD[i2][c] += hiv; }
        }
      }
      Lin = 62;
    } else {
      for (int i = 0; i < 32; ++i) {
        tmpA[i][c] = (c == 2 * i)     ? 1.f : 0.f;
        tmpD[i][c] = (c == 2 * i + 1) ? 1.f : 0.f;
      }
      float cf[4]; int nst;
      if (k == 4) { cf[0] = -0.5f; cf[1] = 0.25f; cf[2] = 0.f; cf[3] = 0.f; nst = 2; }
      else { cf[0] = -1.586134342f; cf[1] = -0.05298011854f;
             cf[2] = 0.8829110762f; cf[3] = 0.4435068522f; nst = 4; }
      for (int s = 0; s < nst; ++s) {
        if ((s & 1) == 0) {
          for (int i = 0; i < 32; ++i) {
            float a = tmpA[(i == 0) ? 1 : i - 1][c];
            float b2 = tmpA[(i == 31) ? 30 : i + 1][c];
            tmpD[i][c] += cf[s] * 0.5f * (a + b2);
          }
        } else {
          for (int i = 0; i < 32; ++i) {
            float a = tmpD[(i == 0) ? 1 : i - 1][c];
            float b2 = tmpD[(i == 31) ? 30 : i + 1][c];
            tmpA[i][c] += cf[s] * 0.5f * (a + b2);
          }
        }
      }
      Lin = 32;
    }
    float sA = 1.f, sD = 1.f;
    if (k == 4) { sA = s53A[0]; sD = s53D[0]; }
    if (k == 5) { sA = s97A[0]; sD = s97D[0]; }
    const float step = (float)Lin / 64.0f;
    for (int o = 0; o < 64; ++o) {
      float src = (o + 0.5f) * step - 0.5f;
      src = fmaxf(src, 0.f);
      int i0 = (int)floorf(src); if (i0 > Lin - 1) i0 = Lin - 1;
      int i1 = i0 + 1;           if (i1 > Lin - 1) i1 = Lin - 1;
      float w = src - (float)i0;
      matA[o][c] = sA * ((1.f - w) * tmpA[i0][c] + w * tmpA[i1][c]);
      matD[o][c] = sD * ((1.f - w) * tmpD[i0][c] + w * tmpD[i1][c]);
    }
  }
  __syncthreads();

  const int o  = q * 16 + (t & 15);
  const int c0 = (t >> 4) * 4;
  float acc[4] = {0.f, 0.f, 0.f, 0.f};
  for (int j = 0; j < 64; ++j) {
    const float wa = pw[o * 128 + j];
    const float wd = pw[o * 128 + 64 + j];
    #pragma unroll
    for (int cc = 0; cc < 4; ++cc)
      acc[cc] += wa * matA[j][c0 + cc] + wd * matD[j][c0 + cc];
  }
  #pragma unroll
  for (int cc = 0; cc < 4; ++cc) {
    const int c = c0 + cc;
    const int s = k * 2 + (c >> 5);
    const int lane = (o & 15) | (((c & 31) >> 3) << 4);
    const int e = c & 7;
    Pout[(((s * 4 + q) * 64 + lane) << 3) + e] = (__bf16)acc[cc];
  }
}

// ---------------------------------------------------------------------------
// Kernel 2: single-barrier, gate-via-MFMA, bf16 transposed LDS tile.
//  2048 blocks x 256 threads; 64 px/block.
//  Phase 0: each thread loads a 4ch x 4px fp32 subtile (4 coalesced f32x4),
//           transposes in-register, writes 4 ds_write_b64 to [px][c] bf16
//           tile (144B row stride -> minimal conflicts both sides).
//  Loop (4 pgs of 16 px): B0/B1 = 2 ds_read_b128; gate h = 2 MFMA (W1@x),
//           logits = per-lane dot4 + shfl_xor butterfly, redundant softmax;
//           main = 12 MFMA + weighted accumulate; 4 dword stores.
// ---------------------------------------------------------------------------
__global__ __launch_bounds__(256, 4) void wavelet_main(
    const float* __restrict__ xg,
    const float* __restrict__ gw1, const float* __restrict__ gb1,
    const float* __restrict__ gw2, const float* __restrict__ gb2,
    const float* __restrict__ pbias,
    const __bf16* __restrict__ Pws,
    float* __restrict__ outg)
{
  __shared__ __align__(16) unsigned char xt[64 * XSTR];   // 9216 B

  const int t     = threadIdx.x;
  const int blk   = blockIdx.x;
  const int b     = blk >> 8;                 // 256 tiles per image
  const int pbase = (blk & 255) << 6;         // 64 px per tile
  const int w     = t >> 6;
  const int lane  = t & 63;
  const int lr    = lane & 15;
  const int kq    = lane >> 4;

  // ---- phase 0: load 4ch x 4px, transpose, write bf16 tile ----
  {
    const int pq = t & 15;
    const int c4 = (t >> 4) << 2;
    const float* src = xg + (size_t)b * (CCH * HW) + (size_t)c4 * HW + pbase + pq * 4;
    f32x4 v[4];
    #pragma unroll
    for (int j = 0; j < 4; ++j) v[j] = *(const f32x4*)(src + (size_t)j * HW);
    #pragma unroll
    for (int i = 0; i < 4; ++i) {
      bf16x4 wv = { (__bf16)v[0][i], (__bf16)v[1][i], (__bf16)v[2][i], (__bf16)v[3][i] };
      *(bf16x4*)&xt[(pq * 4 + i) * XSTR + c4 * 2] = wv;
    }
  }

  // ---- per-wave constant fragments (latency hides under phase 0) ----
  bf16x8 A[12];
  #pragma unroll
  for (int kk = 0; kk < 6; ++kk)
    #pragma unroll
    for (int sh = 0; sh < 2; ++sh)
      A[kk * 2 + sh] = *(const bf16x8*)(Pws + (size_t)((((2 * kk + sh) * 4 + w) * 64 + lane) << 3));

  bf16x8 W1a[2];
  {
    const float* wp = gw1 + lr * 64 + kq * 8;
    #pragma unroll
    for (int hh = 0; hh < 2; ++hh) {
      f32x4 lo = *(const f32x4*)(wp + hh * 32);
      f32x4 hi = *(const f32x4*)(wp + hh * 32 + 4);
      bf16x8 a;
      #pragma unroll
      for (int e = 0; e < 4; ++e) { a[e] = (__bf16)lo[e]; a[e + 4] = (__bf16)hi[e]; }
      W1a[hh] = a;
    }
  }

  f32x4 W2r[6];
  #pragma unroll
  for (int kk = 0; kk < 6; ++kk)
    W2r[kk] = *(const f32x4*)(gw2 + kk * 16 + kq * 4);

  const f32x4 gb1v = *(const f32x4*)(gb1 + kq * 4);

  float bvv[4];
  #pragma unroll
  for (int j = 0; j < 4; ++j) bvv[j] = pbias[w * 16 + kq * 4 + j];

  __syncthreads();

  float* outbase = outg + (size_t)b * (OCH * HW) + pbase;

  #pragma unroll
  for (int pg = 0; pg < 4; ++pg) {
    const int col = pg * 16 + lr;
    const bf16x8 B0 = *(const bf16x8*)&xt[col * XSTR + kq * 16];
    const bf16x8 B1 = *(const bf16x8*)&xt[col * XSTR + 64 + kq * 16];

    // ---- gate: h = relu(W1@x + b1) via MFMA (rows g, cols px) ----
    f32x4 h = {0.f, 0.f, 0.f, 0.f};
    h = __builtin_amdgcn_mfma_f32_16x16x32_bf16(W1a[0], B0, h, 0, 0, 0);
    h = __builtin_amdgcn_mfma_f32_16x16x32_bf16(W1a[1], B1, h, 0, 0, 0);
    float hr[4];
    #pragma unroll
    for (int j = 0; j < 4; ++j) hr[j] = fmaxf(h[j] + gb1v[j], 0.f);

    // logits: per-lane partial dot4 + butterfly sum over the 4 kq groups
    float lg[6];
    #pragma unroll
    for (int kk = 0; kk < 6; ++kk)
      lg[kk] = W2r[kk][0] * hr[0] + W2r[kk][1] * hr[1]
             + W2r[kk][2] * hr[2] + W2r[kk][3] * hr[3];
    #pragma unroll
    for (int kk = 0; kk < 6; ++kk) lg[kk] += __shfl_xor(lg[kk], 16);
    #pragma unroll
    for (int kk = 0; kk < 6; ++kk) lg[kk] += __shfl_xor(lg[kk], 32);
    #pragma unroll
    for (int kk = 0; kk < 6; ++kk) lg[kk] += gb2[kk];

    float mx = fmaxf(fmaxf(fmaxf(lg[0], lg[1]), fmaxf(lg[2], lg[3])), fmaxf(lg[4], lg[5]));
    float ex[6], ssum = 0.f;
    #pragma unroll
    for (int kk = 0; kk < 6; ++kk) { ex[kk] = expf(lg[kk] - mx); ssum += ex[kk]; }
    const float sinv = 1.f / ssum;
    float g6[6], wsum = 0.f;
    #pragma unroll
    for (int kk = 0; kk < 6; ++kk) { g6[kk] = ex[kk] * sinv; wsum += g6[kk]; }
    const float winv = 1.f / (wsum + 1e-12f);
    float wmv[6];
    #pragma unroll
    for (int kk = 0; kk < 6; ++kk) wmv[kk] = g6[kk] * winv;

    // ---- main: 6 weighted P_k @ x products ----
    f32x4 facc = {0.f, 0.f, 0.f, 0.f};
    #pragma unroll
    for (int kk = 0; kk < 6; ++kk) {
      f32x4 y = {0.f, 0.f, 0.f, 0.f};
      y = __builtin_amdgcn_mfma_f32_16x16x32_bf16(A[2 * kk    ], B0, y, 0, 0, 0);
      y = __builtin_amdgcn_mfma_f32_16x16x32_bf16(A[2 * kk + 1], B1, y, 0, 0, 0);
      #pragma unroll
      for (int j = 0; j < 4; ++j) facc[j] += wmv[kk] * y[j];
    }

    #pragma unroll
    for (int j = 0; j < 4; ++j) {
      const int o = w * 16 + kq * 4 + j;
      outbase[(size_t)o * HW + col] = facc[j] + bvv[j];
    }
  }
}

extern "C" void kernel_launch(void* const* d_in, const int* in_sizes, int n_in,
                              void* d_out, int out_size, void* d_ws, size_t ws_size,
                              hipStream_t stream) {
  const float* x    = (const float*)d_in[0];
  const float* gw1  = (const float*)d_in[1];
  const float* gb1  = (const float*)d_in[2];
  const float* gw2  = (const float*)d_in[3];
  const float* gb2  = (const float*)d_in[4];
  const float* pw   = (const float*)d_in[5];
  const float* pb   = (const float*)d_in[6];
  const float* s53A = (const float*)d_in[7];
  const float* s53D = (const float*)d_in[8];
  const float* s97A = (const float*)d_in[9];
  const float* s97D = (const float*)d_in[10];
  __bf16* Pws = (__bf16*)d_ws;
  float* out = (float*)d_out;

  setup_P<<<24, 256, 0, stream>>>(pw, s53A, s53D, s97A, s97D, Pws);
  wavelet_main<<<2048, 256, 0, stream>>>(x, gw1, gb1, gw2, gb2, pb, Pws, out);
}